// Round 1
// baseline (921.697 us; speedup 1.0000x reference)
//
#include <hip/hip_runtime.h>

#define NLAT 361
#define NLON 720
#define LMAX 360
#define MMAX 361
#define NL 8      // nlatent
#define NT 10
#define NB 2
#define BC 16     // NB*NL

static __device__ __forceinline__ float2 cmplx(float a, float b) { float2 r; r.x = a; r.y = b; return r; }

// ---------------- K1: temporal mean over T + last-step delta ----------------
// x: [B][T][C][H][W] fp32.  xu = mean_t(x) [B][C][H][W], xc9 = x[:,T-1]-xu.
__global__ __launch_bounds__(256) void k_mean_sub(const float* __restrict__ x,
                                                  float* __restrict__ xu,
                                                  float* __restrict__ xc9) {
  const int chw4 = NL * NLAT * NLON / 4;   // 519840 float4 per (b,t)
  const int n4   = NB * chw4;              // 1039680
  const float4* x4 = (const float4*)x;
  float4* xu4 = (float4*)xu;
  float4* xc4 = (float4*)xc9;
  for (int i = blockIdx.x * blockDim.x + threadIdx.x; i < n4; i += gridDim.x * blockDim.x) {
    int b = i / chw4, r = i - b * chw4;
    const float4* base = x4 + (long long)b * NT * chw4 + r;
    float4 s = base[0];
    float4 last = s;
    #pragma unroll
    for (int t = 1; t < NT; ++t) {
      float4 v = base[(long long)t * chw4];
      s.x += v.x; s.y += v.y; s.z += v.z; s.w += v.w;
      if (t == NT - 1) last = v;
    }
    float4 u; u.x = s.x * 0.1f; u.y = s.y * 0.1f; u.z = s.z * 0.1f; u.w = s.w * 0.1f;
    float4 d; d.x = last.x - u.x; d.y = last.y - u.y; d.z = last.z - u.z; d.w = last.w - u.w;
    xu4[i] = u; xc4[i] = d;
  }
}

// ---------------- K2: forward real DFT over longitude ----------------
// F_t[bc][m][j] = (2pi/NLON) * wq[j] * sum_w xc9[bc][j][w] e^{-2pi i m w / NLON}
// radix-2 fold: F[m] = sum_{w<360} (x[w] +- x[w+360]) e^{-i m w d}, sign by m parity.
// thread = m (rotation recurrence over w), each thread covers 8 latitude rows.
__global__ __launch_bounds__(384) void k_dft(const float* __restrict__ xc9,
                                             const float* __restrict__ wq,
                                             float2* __restrict__ F_t) {
  const int bc = blockIdx.x;
  const int j0 = blockIdx.y * 8;
  __shared__ float xe[8][360];
  __shared__ float xo[8][360];
  const int tid = threadIdx.x;
  for (int idx = tid; idx < 8 * 360; idx += 384) {
    int r = idx / 360, w = idx - r * 360;
    int j = j0 + r;
    float a = 0.f, b = 0.f;
    if (j < NLAT) {
      const float* row = xc9 + ((long long)bc * NLAT + j) * NLON;
      a = row[w]; b = row[w + 360];
    }
    xe[r][w] = a + b;
    xo[r][w] = a - b;
  }
  __syncthreads();
  const int m = tid;
  if (m < MMAX) {
    const float dphi = 6.2831853071795864769f / (float)NLON;
    float ca = cosf(dphi * (float)m);
    float sa = sinf(dphi * (float)m);
    float cr = 1.f, si = 0.f;   // cos(m w d), sin(m w d)
    const float (*xp)[360] = (m & 1) ? xo : xe;
    float accr[8], acci[8];
    #pragma unroll
    for (int r = 0; r < 8; ++r) { accr[r] = 0.f; acci[r] = 0.f; }
    for (int w = 0; w < 360; ++w) {
      #pragma unroll
      for (int r = 0; r < 8; ++r) {
        float xv = xp[r][w];
        accr[r] = fmaf(xv, cr, accr[r]);
        acci[r] = fmaf(-xv, si, acci[r]);
      }
      float c2 = fmaf(cr, ca, -si * sa);
      float s2 = fmaf(si, ca, cr * sa);
      cr = c2; si = s2;
    }
    #pragma unroll
    for (int r = 0; r < 8; ++r) {
      int j = j0 + r;
      if (j < NLAT) {
        float scale = wq[j] * (6.2831853071795864769f / (float)NLON);
        F_t[((long long)bc * MMAX + m) * NLAT + j] = cmplx(accr[r] * scale, acci[r] * scale);
      }
    }
  }
}

// ---------------- K3: Legendre analysis ----------------
// x_sht[l][m][bc] = sum_j leg[l][m][j] * F_t[bc][m][j]      (wq folded into F_t)
// block = (m, l-tile of 16); thread = (li, bc); j staged in 64-chunks.
__global__ __launch_bounds__(256) void k_analysis(const float* __restrict__ leg,
                                                  const float2* __restrict__ F_t,
                                                  float2* __restrict__ x_sht) {
  const int m  = blockIdx.x;
  const int l0 = blockIdx.y * 16;
  const int tid = threadIdx.x;
  const int li = tid >> 4, bcid = tid & 15;
  __shared__ float  legs[16][65];   // +1 pad: conflict-free
  __shared__ float2 Fs[16][65];     // [bc][j]
  float ar = 0.f, ai = 0.f;
  for (int jb = 0; jb < NLAT; jb += 64) {
    __syncthreads();
    for (int idx = tid; idx < 16 * 64; idx += 256) {
      int r = idx >> 6, c = idx & 63;
      int gl = l0 + r, j = jb + c;
      legs[r][c] = (gl < LMAX && j < NLAT) ? leg[((long long)gl * MMAX + m) * NLAT + j] : 0.f;
      Fs[r][c]   = (j < NLAT) ? F_t[((long long)r * MMAX + m) * NLAT + j] : cmplx(0.f, 0.f);
    }
    __syncthreads();
    #pragma unroll 8
    for (int c = 0; c < 64; ++c) {
      float lw = legs[li][c];
      float2 f = Fs[bcid][c];
      ar = fmaf(lw, f.x, ar);
      ai = fmaf(lw, f.y, ai);
    }
  }
  if (l0 + li < LMAX)
    x_sht[((long long)(l0 + li) * MMAX + m) * BC + bcid] = cmplx(ar, ai);
}

// ---------------- K4: complex channel mix + residual ----------------
// y[b,C,lm] = sum_c (A + i Ai)[C,c,lm] * x[b,c,lm] + x[b,C,lm]
__global__ __launch_bounds__(256) void k_mix(const float* __restrict__ A,
                                             const float* __restrict__ Ai,
                                             const float2* __restrict__ xs,
                                             float2* __restrict__ ys) {
  const int lm = blockIdx.x * blockDim.x + threadIdx.x;
  if (lm >= LMAX * MMAX) return;
  float2 xv[16], acc[16];
  const float2* xp = xs + (long long)lm * BC;
  #pragma unroll
  for (int i = 0; i < 16; ++i) { xv[i] = xp[i]; acc[i] = xv[i]; }
  #pragma unroll
  for (int C = 0; C < 8; ++C) {
    #pragma unroll
    for (int c = 0; c < 8; ++c) {
      long long off = (long long)(C * 8 + c) * (LMAX * MMAX) + lm;
      float a = A[off];
      float b = Ai[off];
      #pragma unroll
      for (int bb = 0; bb < 2; ++bb) {
        float2 xin = xv[bb * 8 + c];
        acc[bb * 8 + C].x += a * xin.x - b * xin.y;
        acc[bb * 8 + C].y += a * xin.y + b * xin.x;
      }
    }
  }
  float2* yp = ys + (long long)lm * BC;
  #pragma unroll
  for (int i = 0; i < 16; ++i) yp[i] = acc[i];
}

// ---------------- K5: Legendre synthesis ----------------
// Fm_t[bc][m][j] = sum_l leg[l][m][j] * y_sht[l][m][bc]
// block = (m, j-tile of 16); thread = (j_local, bc); l staged in chunks of 8.
__global__ __launch_bounds__(256) void k_synth(const float* __restrict__ leg,
                                               const float2* __restrict__ y_sht,
                                               float2* __restrict__ Fm_t) {
  const int m  = blockIdx.x;
  const int j0 = blockIdx.y * 16;
  const int tid = threadIdx.x;
  const int jl = tid & 15, bcid = tid >> 4;
  __shared__ float  legs[8][17];
  __shared__ float2 ysd[8][16];
  float ar = 0.f, ai = 0.f;
  for (int l0 = 0; l0 < LMAX; l0 += 8) {
    __syncthreads();
    if (tid < 128) {
      int r = tid >> 4, c = tid & 15;
      int j = j0 + c;
      legs[r][c] = (j < NLAT) ? leg[((long long)(l0 + r) * MMAX + m) * NLAT + j] : 0.f;
    } else {
      int t2 = tid - 128;
      int r = t2 >> 4, b = t2 & 15;
      ysd[r][b] = y_sht[((long long)(l0 + r) * MMAX + m) * BC + b];
    }
    __syncthreads();
    #pragma unroll
    for (int rr = 0; rr < 8; ++rr) {
      float lw = legs[rr][jl];
      float2 yv = ysd[rr][bcid];
      ar = fmaf(lw, yv.x, ar);
      ai = fmaf(lw, yv.y, ai);
    }
  }
  int j = j0 + jl;
  if (j < NLAT)
    Fm_t[((long long)bcid * MMAX + m) * NLAT + j] = cmplx(ar, ai);
}

// ---------------- K6: inverse real DFT + add xu ----------------
// y[w] = Re F0 + 2 sum_{1..359}(Re F cos - Im F sin) + Re F360 (-1)^w ; out = y + xu
// even/odd m split: compute w and w+360 together. thread = w, 8 rows per block.
__global__ __launch_bounds__(384) void k_idft(const float2* __restrict__ Fm_t,
                                              const float* __restrict__ xu,
                                              float* __restrict__ out) {
  const int bc = blockIdx.x;
  const int j0 = blockIdx.y * 8;
  __shared__ float2 Fs[MMAX][8];
  const int tid = threadIdx.x;
  for (int idx = tid; idx < MMAX * 8; idx += 384) {
    int mr = idx >> 3, c = idx & 7;
    int j = j0 + c;
    Fs[mr][c] = (j < NLAT) ? Fm_t[((long long)bc * MMAX + mr) * NLAT + j] : cmplx(0.f, 0.f);
  }
  __syncthreads();
  const int w = tid;
  if (w < 360) {
    const float dphi = 6.2831853071795864769f / (float)NLON;
    float ca = cosf(dphi * (float)w);
    float sa = sinf(dphi * (float)w);
    float cr = ca, si = sa;   // angle = m*w*d starting at m=1
    float E[8], O[8];
    const float s360 = (w & 1) ? -0.5f : 0.5f;
    #pragma unroll
    for (int r = 0; r < 8; ++r) {
      E[r] = 0.5f * Fs[0][r].x + s360 * Fs[360][r].x;
      O[r] = 0.f;
    }
    for (int m = 1; m < 360; m += 2) {
      #pragma unroll
      for (int r = 0; r < 8; ++r) {           // odd m
        float2 f = Fs[m][r];
        O[r] = fmaf(f.x, cr, O[r]);
        O[r] = fmaf(-f.y, si, O[r]);
      }
      { float c2 = fmaf(cr, ca, -si * sa); float s2 = fmaf(si, ca, cr * sa); cr = c2; si = s2; }
      if (m + 1 < 360) {
        #pragma unroll
        for (int r = 0; r < 8; ++r) {         // even m+1
          float2 f = Fs[m + 1][r];
          E[r] = fmaf(f.x, cr, E[r]);
          E[r] = fmaf(-f.y, si, E[r]);
        }
        { float c2 = fmaf(cr, ca, -si * sa); float s2 = fmaf(si, ca, cr * sa); cr = c2; si = s2; }
      }
    }
    #pragma unroll
    for (int r = 0; r < 8; ++r) {
      int j = j0 + r;
      if (j < NLAT) {
        long long gi = ((long long)bc * NLAT + j) * NLON;
        out[gi + w]       = 2.f * (E[r] + O[r]) + xu[gi + w];
        out[gi + w + 360] = 2.f * (E[r] - O[r]) + xu[gi + w + 360];
      }
    }
  }
}

extern "C" void kernel_launch(void* const* d_in, const int* in_sizes, int n_in,
                              void* d_out, int out_size, void* d_ws, size_t ws_size,
                              hipStream_t stream) {
  (void)in_sizes; (void)n_in; (void)out_size; (void)ws_size;
  const float* x   = (const float*)d_in[0];
  const float* A   = (const float*)d_in[1];
  const float* Ai  = (const float*)d_in[2];
  const float* leg = (const float*)d_in[3];
  const float* wq  = (const float*)d_in[4];
  float* out = (float*)d_out;
  float* ws  = (float*)d_ws;

  const long long SZ = (long long)BC * NLAT * NLON;   // 4,158,720 floats
  float*  xu   = ws;                                   // [bc][j][w]
  float*  xc9  = ws + SZ;                              // reused as y_sht after k_dft
  float2* F_t  = (float2*)(ws + 2 * SZ);               // [bc][m][j] complex (4,169,472 floats)
  float2* xsht = (float2*)(ws + 2 * SZ + (long long)BC * MMAX * NLAT * 2);  // [l][m][bc]
  float2* ysht = (float2*)xc9;                         // [l][m][bc]
  float2* Fm_t = F_t;                                  // reuse: [bc][m][j]

  k_mean_sub<<<2048, 256, 0, stream>>>(x, xu, xc9);
  k_dft<<<dim3(16, 46), 384, 0, stream>>>(xc9, wq, F_t);
  k_analysis<<<dim3(361, 23), 256, 0, stream>>>(leg, F_t, xsht);
  k_mix<<<(LMAX * MMAX + 255) / 256, 256, 0, stream>>>(A, Ai, xsht, ysht);
  k_synth<<<dim3(361, 23), 256, 0, stream>>>(leg, ysht, Fm_t);
  k_idft<<<dim3(16, 46), 384, 0, stream>>>(Fm_t, xu, out);
}

// Round 2
// 655.746 us; speedup vs baseline: 1.4056x; 1.4056x over previous
//
#include <hip/hip_runtime.h>

#define NLAT 361
#define NLON 720
#define LMAX 360
#define MMAX 361
#define NL 8      // nlatent
#define NT 10
#define NB 2
#define BC 16     // NB*NL

static __device__ __forceinline__ float2 cmplx(float a, float b) { float2 r; r.x = a; r.y = b; return r; }

// ---------------- K1: temporal mean over T + last-step delta ----------------
__global__ __launch_bounds__(256) void k_mean_sub(const float* __restrict__ x,
                                                  float* __restrict__ xu,
                                                  float* __restrict__ xc9) {
  const int chw4 = NL * NLAT * NLON / 4;
  const int n4   = NB * chw4;
  const float4* x4 = (const float4*)x;
  float4* xu4 = (float4*)xu;
  float4* xc4 = (float4*)xc9;
  for (int i = blockIdx.x * blockDim.x + threadIdx.x; i < n4; i += gridDim.x * blockDim.x) {
    int b = i / chw4, r = i - b * chw4;
    const float4* base = x4 + (long long)b * NT * chw4 + r;
    float4 s = base[0];
    float4 last = s;
    #pragma unroll
    for (int t = 1; t < NT; ++t) {
      float4 v = base[(long long)t * chw4];
      s.x += v.x; s.y += v.y; s.z += v.z; s.w += v.w;
      if (t == NT - 1) last = v;
    }
    float4 u; u.x = s.x * 0.1f; u.y = s.y * 0.1f; u.z = s.z * 0.1f; u.w = s.w * 0.1f;
    float4 d; d.x = last.x - u.x; d.y = last.y - u.y; d.z = last.z - u.z; d.w = last.w - u.w;
    xu4[i] = u; xc4[i] = d;
  }
}

// ---------------- K2: forward real DFT over longitude ----------------
// F_t[bc][m][j] = (2pi/NLON)*wq[j]* sum_w xc9[bc][j][w] e^{-i m w dphi}; radix-2 fold over w.
// LDS transposed [w][r] so the per-m loop reads broadcast float4s.
__global__ __launch_bounds__(384) void k_dft(const float* __restrict__ xc9,
                                             const float* __restrict__ wq,
                                             float2* __restrict__ F_t) {
  const int bc = blockIdx.x;
  const int j0 = blockIdx.y * 8;
  __shared__ float xef[360][12];   // pad 12: rows 48B (16B aligned), writes ~2-way
  __shared__ float xof[360][12];
  const int tid = threadIdx.x;
  for (int idx = tid; idx < 2880; idx += 384) {
    int r = idx & 7, w = idx >> 3;
    int j = j0 + r;
    float a = 0.f, b = 0.f;
    if (j < NLAT) {
      const float* row = xc9 + ((long long)bc * NLAT + j) * NLON;
      a = row[w]; b = row[w + 360];
    }
    xef[w][r] = a + b;
    xof[w][r] = a - b;
  }
  __syncthreads();
  const int m = tid;
  if (m < MMAX) {
    const float dphi = 6.2831853071795864769f / (float)NLON;
    float ca = cosf(dphi * (float)m);
    float sa = sinf(dphi * (float)m);
    float cr = 1.f, si = 0.f;
    const float (*xp)[12] = (m & 1) ? xof : xef;
    float accr[8], acci[8];
    #pragma unroll
    for (int r = 0; r < 8; ++r) { accr[r] = 0.f; acci[r] = 0.f; }
    for (int w = 0; w < 360; ++w) {
      float4 v0 = *(const float4*)&xp[w][0];
      float4 v1 = *(const float4*)&xp[w][4];
      float xv[8] = {v0.x, v0.y, v0.z, v0.w, v1.x, v1.y, v1.z, v1.w};
      #pragma unroll
      for (int r = 0; r < 8; ++r) {
        accr[r] = fmaf(xv[r], cr, accr[r]);
        acci[r] = fmaf(-xv[r], si, acci[r]);
      }
      float c2 = fmaf(cr, ca, -si * sa);
      float s2 = fmaf(si, ca, cr * sa);
      cr = c2; si = s2;
    }
    float2* op = F_t + ((long long)bc * MMAX + m) * NLAT + j0;
    #pragma unroll
    for (int r = 0; r < 8; ++r) {
      int j = j0 + r;
      if (j < NLAT) {
        float scale = wq[j] * (6.2831853071795864769f / (float)NLON);
        op[r] = cmplx(accr[r] * scale, acci[r] * scale);
      }
    }
  }
}

// ---------------- K3: Legendre analysis (parity-folded) ----------------
// x_sht[l][m][bc] = sum_{j<=180} leg[l][m][j] * (F[j] +- F[360-j])   (sign = (-1)^(l+m))
// grid (MMAX, 3) l-tiles of 128; thread: 4 l (same parity, b128) x 2 bc.
__global__ __launch_bounds__(256) void k_analysis(const float* __restrict__ leg,
                                                  const float2* __restrict__ F_t,
                                                  float2* __restrict__ x_sht) {
  const int m  = blockIdx.x;
  const int L0 = blockIdx.y * 128;
  const int tid = threadIdx.x;
  const int bcg = tid & 7;
  const int lg  = (tid >> 3) & 15;
  const int q   = tid >> 7;             // l parity (L0 even)
  if (m > L0 + 127) {                   // whole tile has l < m -> leg==0 -> zeros
    #pragma unroll
    for (int u = 0; u < 4; ++u) {
      int l = L0 + 8 * lg + 2 * u + q;
      if (l < LMAX) {
        long long o = ((long long)l * MMAX + m) * BC + 2 * bcg;
        x_sht[o] = cmplx(0.f, 0.f);
        x_sht[o + 1] = cmplx(0.f, 0.f);
      }
    }
    return;
  }
  __shared__ float  legT[2][32][68];    // [q][c][k], k=(l-L0-q)/2 ; stride 68 -> b128-aligned
  __shared__ float2 Ff[2][16][33];      // [sel][bc][c]
  float2 acc[4][2];
  #pragma unroll
  for (int u = 0; u < 4; ++u) { acc[u][0] = cmplx(0.f, 0.f); acc[u][1] = cmplx(0.f, 0.f); }
  const int sel = (q + m) & 1;
  for (int jb = 0; jb < 192; jb += 32) {
    __syncthreads();
    // stage legT: 128 rows x 32 j (scalar: leg rows are not 16B-aligned)
    for (int idx = tid; idx < 4096; idx += 256) {
      int ll = idx >> 5, c = idx & 31;
      int gl = L0 + ll;
      float v = 0.f;
      if (gl < LMAX) v = leg[((long long)gl * MMAX + m) * NLAT + jb + c];  // j<=191 in-bounds
      legT[ll & 1][c][ll >> 1] = v;
    }
    // stage folded F
    for (int idx = tid; idx < 512; idx += 256) {
      int b = idx >> 5, c = idx & 31;
      int j = jb + c;
      float2 fp = cmplx(0.f, 0.f), fm = cmplx(0.f, 0.f);
      if (j < 180) {
        float2 va = F_t[((long long)b * MMAX + m) * NLAT + j];
        float2 vb = F_t[((long long)b * MMAX + m) * NLAT + (360 - j)];
        fp = cmplx(va.x + vb.x, va.y + vb.y);
        fm = cmplx(va.x - vb.x, va.y - vb.y);
      } else if (j == 180) {
        fp = F_t[((long long)b * MMAX + m) * NLAT + 180];
      }
      Ff[0][b][c] = fp;
      Ff[1][b][c] = fm;
    }
    __syncthreads();
    #pragma unroll 4
    for (int c = 0; c < 32; ++c) {
      float4 lw = *(const float4*)&legT[q][c][4 * lg];
      float2 f0 = Ff[sel][2 * bcg][c];
      float2 f1 = Ff[sel][2 * bcg + 1][c];
      acc[0][0].x = fmaf(lw.x, f0.x, acc[0][0].x); acc[0][0].y = fmaf(lw.x, f0.y, acc[0][0].y);
      acc[0][1].x = fmaf(lw.x, f1.x, acc[0][1].x); acc[0][1].y = fmaf(lw.x, f1.y, acc[0][1].y);
      acc[1][0].x = fmaf(lw.y, f0.x, acc[1][0].x); acc[1][0].y = fmaf(lw.y, f0.y, acc[1][0].y);
      acc[1][1].x = fmaf(lw.y, f1.x, acc[1][1].x); acc[1][1].y = fmaf(lw.y, f1.y, acc[1][1].y);
      acc[2][0].x = fmaf(lw.z, f0.x, acc[2][0].x); acc[2][0].y = fmaf(lw.z, f0.y, acc[2][0].y);
      acc[2][1].x = fmaf(lw.z, f1.x, acc[2][1].x); acc[2][1].y = fmaf(lw.z, f1.y, acc[2][1].y);
      acc[3][0].x = fmaf(lw.w, f0.x, acc[3][0].x); acc[3][0].y = fmaf(lw.w, f0.y, acc[3][0].y);
      acc[3][1].x = fmaf(lw.w, f1.x, acc[3][1].x); acc[3][1].y = fmaf(lw.w, f1.y, acc[3][1].y);
    }
  }
  #pragma unroll
  for (int u = 0; u < 4; ++u) {
    int l = L0 + 8 * lg + 2 * u + q;
    if (l < LMAX) {
      long long o = ((long long)l * MMAX + m) * BC + 2 * bcg;
      x_sht[o] = acc[u][0];
      x_sht[o + 1] = acc[u][1];
    }
  }
}

// ---------------- K4: complex channel mix + residual (skip l<m) ----------------
__global__ __launch_bounds__(256) void k_mix(const float* __restrict__ A,
                                             const float* __restrict__ Ai,
                                             const float2* __restrict__ xs,
                                             float2* __restrict__ ys) {
  const int lm = blockIdx.x * blockDim.x + threadIdx.x;
  if (lm >= LMAX * MMAX) return;
  const int l = lm / MMAX, mm = lm - l * MMAX;
  float2* yp = ys + (long long)lm * BC;
  if (l < mm) {                          // leg==0 -> x_sht==0 -> y==0
    #pragma unroll
    for (int i = 0; i < 16; ++i) yp[i] = cmplx(0.f, 0.f);
    return;
  }
  float2 xv[16], acc[16];
  const float2* xp = xs + (long long)lm * BC;
  #pragma unroll
  for (int i = 0; i < 16; ++i) { xv[i] = xp[i]; acc[i] = xv[i]; }
  #pragma unroll
  for (int C = 0; C < 8; ++C) {
    #pragma unroll
    for (int c = 0; c < 8; ++c) {
      long long off = (long long)(C * 8 + c) * (LMAX * MMAX) + lm;
      float a = A[off];
      float b = Ai[off];
      #pragma unroll
      for (int bb = 0; bb < 2; ++bb) {
        float2 xin = xv[bb * 8 + c];
        acc[bb * 8 + C].x += a * xin.x - b * xin.y;
        acc[bb * 8 + C].y += a * xin.y + b * xin.x;
      }
    }
  }
  #pragma unroll
  for (int i = 0; i < 16; ++i) yp[i] = acc[i];
}

// ---------------- K5: Legendre synthesis (parity-folded, E/O split) ----------------
// Fm_t[bc][m][j] = sE+sO at j, (-1)^m (sE-sO) at 360-j; chunks start at m&~31 (l>=m only).
__global__ __launch_bounds__(256) void k_synth(const float* __restrict__ leg,
                                               const float2* __restrict__ y_sht,
                                               float2* __restrict__ Fm_t) {
  const int m  = blockIdx.x;
  const int J0 = blockIdx.y * 64;
  const int tid = threadIdx.x;
  const int bcg = tid & 7;
  const int jg  = tid >> 3;            // 0..31
  const int j   = J0 + 2 * jg;
  __shared__ float  legs[32][68];      // [l_local][j_local]
  __shared__ float2 ys[32][16];
  float2 sE[2][2], sO[2][2];
  #pragma unroll
  for (int a = 0; a < 2; ++a)
    #pragma unroll
    for (int b = 0; b < 2; ++b) { sE[a][b] = cmplx(0.f, 0.f); sO[a][b] = cmplx(0.f, 0.f); }
  const int first = (m > 31) ? (m & ~31) : 0;
  for (int l0 = first; l0 < LMAX; l0 += 32) {
    __syncthreads();
    for (int idx = tid; idx < 2048; idx += 256) {
      int ll = idx >> 6, c = idx & 63;
      int gl = l0 + ll;
      legs[ll][c] = (gl < LMAX) ? leg[((long long)gl * MMAX + m) * NLAT + J0 + c] : 0.f;
    }
    for (int idx = tid; idx < 512; idx += 256) {
      int ll = idx >> 4, b = idx & 15;
      int gl = l0 + ll;
      ys[ll][b] = (gl < LMAX) ? y_sht[((long long)gl * MMAX + m) * BC + b] : cmplx(0.f, 0.f);
    }
    __syncthreads();
    #pragma unroll 8
    for (int kk = 0; kk < 32; ++kk) {
      float2 lw = *(const float2*)&legs[kk][2 * jg];
      float4 yv = *(const float4*)&ys[kk][2 * bcg];   // (y0.x,y0.y,y1.x,y1.y)
      if ((kk & 1) == 0) {        // l0 multiples of 32 -> kk even == l even
        sE[0][0].x = fmaf(lw.x, yv.x, sE[0][0].x); sE[0][0].y = fmaf(lw.x, yv.y, sE[0][0].y);
        sE[0][1].x = fmaf(lw.x, yv.z, sE[0][1].x); sE[0][1].y = fmaf(lw.x, yv.w, sE[0][1].y);
        sE[1][0].x = fmaf(lw.y, yv.x, sE[1][0].x); sE[1][0].y = fmaf(lw.y, yv.y, sE[1][0].y);
        sE[1][1].x = fmaf(lw.y, yv.z, sE[1][1].x); sE[1][1].y = fmaf(lw.y, yv.w, sE[1][1].y);
      } else {
        sO[0][0].x = fmaf(lw.x, yv.x, sO[0][0].x); sO[0][0].y = fmaf(lw.x, yv.y, sO[0][0].y);
        sO[0][1].x = fmaf(lw.x, yv.z, sO[0][1].x); sO[0][1].y = fmaf(lw.x, yv.w, sO[0][1].y);
        sO[1][0].x = fmaf(lw.y, yv.x, sO[1][0].x); sO[1][0].y = fmaf(lw.y, yv.y, sO[1][0].y);
        sO[1][1].x = fmaf(lw.y, yv.z, sO[1][1].x); sO[1][1].y = fmaf(lw.y, yv.w, sO[1][1].y);
      }
    }
  }
  const float sm = (m & 1) ? -1.f : 1.f;
  #pragma unroll
  for (int jj = 0; jj < 2; ++jj) {
    int pj = j + jj;
    if (pj > 180) continue;
    #pragma unroll
    for (int b = 0; b < 2; ++b) {
      float2 v1 = cmplx(sE[jj][b].x + sO[jj][b].x, sE[jj][b].y + sO[jj][b].y);
      Fm_t[((long long)(2 * bcg + b) * MMAX + m) * NLAT + pj] = v1;
      if (pj < 180) {
        float2 v2 = cmplx(sm * (sE[jj][b].x - sO[jj][b].x), sm * (sE[jj][b].y - sO[jj][b].y));
        Fm_t[((long long)(2 * bcg + b) * MMAX + m) * NLAT + (360 - pj)] = v2;
      }
    }
  }
}

// ---------------- K6: inverse real DFT + add xu ----------------
__global__ __launch_bounds__(384) void k_idft(const float2* __restrict__ Fm_t,
                                              const float* __restrict__ xu,
                                              float* __restrict__ out) {
  const int bc = blockIdx.x;
  const int j0 = blockIdx.y * 8;
  __shared__ float2 Fs[MMAX][10];     // pad 10: rows 80B (16B aligned)
  const int tid = threadIdx.x;
  for (int idx = tid; idx < MMAX * 8; idx += 384) {
    int mr = idx >> 3, c = idx & 7;
    int jj = j0 + c;
    Fs[mr][c] = (jj < NLAT) ? Fm_t[((long long)bc * MMAX + mr) * NLAT + jj] : cmplx(0.f, 0.f);
  }
  __syncthreads();
  const int w = tid;
  if (w < 360) {
    const float dphi = 6.2831853071795864769f / (float)NLON;
    float ca = cosf(dphi * (float)w);
    float sa = sinf(dphi * (float)w);
    float cr = ca, si = sa;   // angle = m*w*dphi starting at m=1
    float E[8], O[8];
    const float s360 = (w & 1) ? -0.5f : 0.5f;
    {
      const float4* f0 = (const float4*)&Fs[0][0];
      const float4* f360 = (const float4*)&Fs[360][0];
      float r0[8] = {f0[0].x, f0[0].z, f0[1].x, f0[1].z, f0[2].x, f0[2].z, f0[3].x, f0[3].z};
      float r3[8] = {f360[0].x, f360[0].z, f360[1].x, f360[1].z, f360[2].x, f360[2].z, f360[3].x, f360[3].z};
      #pragma unroll
      for (int r = 0; r < 8; ++r) { E[r] = 0.5f * r0[r] + s360 * r3[r]; O[r] = 0.f; }
    }
    for (int m = 1; m < 360; m += 2) {
      {
        const float4* fm4 = (const float4*)&Fs[m][0];
        float4 p0 = fm4[0], p1 = fm4[1], p2 = fm4[2], p3 = fm4[3];
        float fr[8] = {p0.x, p0.z, p1.x, p1.z, p2.x, p2.z, p3.x, p3.z};
        float fi[8] = {p0.y, p0.w, p1.y, p1.w, p2.y, p2.w, p3.y, p3.w};
        #pragma unroll
        for (int r = 0; r < 8; ++r) {
          O[r] = fmaf(fr[r], cr, O[r]);
          O[r] = fmaf(-fi[r], si, O[r]);
        }
      }
      { float c2 = fmaf(cr, ca, -si * sa); float s2 = fmaf(si, ca, cr * sa); cr = c2; si = s2; }
      {
        const float4* fm4 = (const float4*)&Fs[m + 1][0];
        float4 p0 = fm4[0], p1 = fm4[1], p2 = fm4[2], p3 = fm4[3];
        float fr[8] = {p0.x, p0.z, p1.x, p1.z, p2.x, p2.z, p3.x, p3.z};
        float fi[8] = {p0.y, p0.w, p1.y, p1.w, p2.y, p2.w, p3.y, p3.w};
        #pragma unroll
        for (int r = 0; r < 8; ++r) {
          E[r] = fmaf(fr[r], cr, E[r]);
          E[r] = fmaf(-fi[r], si, E[r]);
        }
      }
      { float c2 = fmaf(cr, ca, -si * sa); float s2 = fmaf(si, ca, cr * sa); cr = c2; si = s2; }
    }
    #pragma unroll
    for (int r = 0; r < 8; ++r) {
      int jj = j0 + r;
      if (jj < NLAT) {
        long long gi = ((long long)bc * NLAT + jj) * NLON;
        out[gi + w]       = 2.f * (E[r] + O[r]) + xu[gi + w];
        out[gi + w + 360] = 2.f * (E[r] - O[r]) + xu[gi + w + 360];
      }
    }
  }
}

extern "C" void kernel_launch(void* const* d_in, const int* in_sizes, int n_in,
                              void* d_out, int out_size, void* d_ws, size_t ws_size,
                              hipStream_t stream) {
  (void)in_sizes; (void)n_in; (void)out_size; (void)ws_size;
  const float* x   = (const float*)d_in[0];
  const float* A   = (const float*)d_in[1];
  const float* Ai  = (const float*)d_in[2];
  const float* leg = (const float*)d_in[3];
  const float* wq  = (const float*)d_in[4];
  float* out = (float*)d_out;
  float* ws  = (float*)d_ws;

  const long long SZ = (long long)BC * NLAT * NLON;   // 4,158,720 floats
  float*  xu   = ws;                                   // [bc][j][w]
  float*  xc9  = ws + SZ;                              // reused as y_sht after k_dft
  float2* F_t  = (float2*)(ws + 2 * SZ);               // [bc][m][j]
  float2* xsht = (float2*)(ws + 2 * SZ + (long long)BC * MMAX * NLAT * 2);  // [l][m][bc]
  float2* ysht = (float2*)xc9;                         // [l][m][bc]
  float2* Fm_t = F_t;                                  // reuse: [bc][m][j]

  k_mean_sub<<<2048, 256, 0, stream>>>(x, xu, xc9);
  k_dft<<<dim3(16, 46), 384, 0, stream>>>(xc9, wq, F_t);
  k_analysis<<<dim3(361, 3), 256, 0, stream>>>(leg, F_t, xsht);
  k_mix<<<(LMAX * MMAX + 255) / 256, 256, 0, stream>>>(A, Ai, xsht, ysht);
  k_synth<<<dim3(361, 3), 256, 0, stream>>>(leg, ysht, Fm_t);
  k_idft<<<dim3(16, 46), 384, 0, stream>>>(Fm_t, xu, out);
}